// Round 7
// baseline (213.620 us; speedup 1.0000x reference)
//
#include <hip/hip_runtime.h>
#include <math.h>

// NT=64, NR=4, DK=2, KU=8, BR=16, BATCH=256
// channel:    [B][64][4][16][16] f32 (last dim: 8 re, 8 im)
// prediction: [B][2560] = U[4][2][16][16] ++ W[2][2][16][8]
// out:        [B][64][2][8][2] f32
//
// R7: wave-private f decomposition. Wave wv handles f = 2wv, 2wv+1 with NO
// phase-1 barriers: lane l owns H row t=l (r-sum is lane-local, butterfly
// gone), writes T/H m-pair tiles to a private LDS region (swizzle t'=t+(t>>3)
// -> conflict-free b128), accumulates a full 64x64 qacc partial in 8x8
// register tiles. Partials merged via a 3-round staging tree in the tile
// region; HUW via per-wave dumps; tr_UWU via LDS float atomics.
// GJ (register-resident rows, diagonal pivots) and epilogue = R6 verbatim.

#define TPF4   1136    // per-wave tile: 16 rows x 71 float4
#define AUGF4  43      // Aug row stride (float4)
#define AUGF2  86      // Aug row stride (float2)
#define SBASE  2752    // staging base (float4) = 64*43
#define SSTR   2112    // staging slot stride (float4) = 64*33

namespace {
union alignas(16) ShV {
    struct { float2 U[4*258]; float W[512]; } in;          // 10304 B
    struct { float2 xout[64][17]; float2 prow[2][80]; } gj; // 9984 B
};
}

__device__ __forceinline__ float2 cmul(float2 a, float2 b) {
    return make_float2(a.x*b.x - a.y*b.y, a.x*b.y + a.y*b.x);
}

__global__ __launch_bounds__(512, 2)
void uw2v_kernel(const float* __restrict__ channel,
                 const float* __restrict__ prediction,
                 float2* __restrict__ out)
{
    __shared__ float4 tile[9088];          // 145408 B (tiles | Aug+staging)
    __shared__ ShV sv;
    __shared__ float fred[8];
    __shared__ float trUW[2];

    const int b   = blockIdx.x;
    const int tid = threadIdx.x;
    const int wv  = tid >> 6, ln = tid & 63;
    const float* pred = prediction + (size_t)b * 2560;
    const float* chan = channel + (size_t)b * 65536;

    if (tid == 0) { trUW[0] = 0.f; trUW[1] = 0.f; }
    #pragma unroll
    for (int i = 0; i < 2; ++i) {
        int m = tid + i*512;                    // [r][d][f][k]
        int r = m >> 8, d = (m >> 7) & 1, f = (m >> 3) & 15, k = m & 7;
        const float* src = pred + (((r*2+d)*16+f) << 4);
        sv.in.U[r*258 + ((d*16+f) << 3) + k] = make_float2(src[k], src[k+8]);
    }
    sv.in.W[tid] = pred[2048 + tid];
    __syncthreads();

    const int l8 = ln >> 3, llo = ln & 7;
    const int tp = ln + l8;                    // swizzled column t'
    const int wbase = wv * TPF4;
    const float4* U4 = (const float4*)sv.in.U;
    const float4* W4 = (const float4*)sv.in.W;

    float2 qacc[8][8];
    #pragma unroll
    for (int i = 0; i < 8; ++i)
        #pragma unroll
        for (int j = 0; j < 8; ++j) qacc[i][j] = make_float2(0.f, 0.f);
    float2 huw[16];
    #pragma unroll
    for (int m = 0; m < 16; ++m) huw[m] = make_float2(0.f, 0.f);
    float2 tracc = make_float2(0.f, 0.f);

    #pragma unroll 1
    for (int ff = 0; ff < 2; ++ff) {
        const int f = wv*2 + ff;
        float2 hh0[8], hh1[8];
        #pragma unroll
        for (int k = 0; k < 8; ++k) { hh0[k] = make_float2(0.f,0.f); hh1[k] = make_float2(0.f,0.f); }

        // HHU[t=ln][d][k] = sum_r conj(H[t][r][f][k]) * U[r][d][f][k]
        const float* hb = chan + (ln << 10) + (f << 4);
        #pragma unroll
        for (int r = 0; r < 4; ++r) {
            const float* hp = hb + (r << 8);
            float4 hra = *(const float4*)(hp + 0);
            float4 hrb = *(const float4*)(hp + 4);
            float4 hia = *(const float4*)(hp + 8);
            float4 hib = *(const float4*)(hp + 12);
            const float4* u0p = U4 + r*129 + 4*f;   // d=0
            const float4* u1p = u0p + 64;           // d=1
            float4 u00=u0p[0], u01=u0p[1], u02=u0p[2], u03=u0p[3];
            float4 u10=u1p[0], u11=u1p[1], u12=u1p[2], u13=u1p[3];
            #define CMAC(K, HR, HI, R0, I0, R1, I1) \
                hh0[K].x += (HR)*(R0) + (HI)*(I0); hh0[K].y += (HR)*(I0) - (HI)*(R0); \
                hh1[K].x += (HR)*(R1) + (HI)*(I1); hh1[K].y += (HR)*(I1) - (HI)*(R1);
            CMAC(0, hra.x, hia.x, u00.x,u00.y, u10.x,u10.y)
            CMAC(1, hra.y, hia.y, u00.z,u00.w, u10.z,u10.w)
            CMAC(2, hra.z, hia.z, u01.x,u01.y, u11.x,u11.y)
            CMAC(3, hra.w, hia.w, u01.z,u01.w, u11.z,u11.w)
            CMAC(4, hrb.x, hib.x, u02.x,u02.y, u12.x,u12.y)
            CMAC(5, hrb.y, hib.y, u02.z,u02.w, u12.z,u12.w)
            CMAC(6, hrb.z, hib.z, u03.x,u03.y, u13.x,u13.y)
            CMAC(7, hrb.w, hib.w, u03.z,u03.w, u13.z,u13.w)
            #undef CMAC
        }

        // tr_UWU: lane covers (r2,d2,k2) x e in {0,1}
        {
            const int r2 = ln >> 4, d2 = (ln >> 3) & 1, k2 = ln & 7;
            float2 uu  = sv.in.U[r2*258 + ((d2*16+f) << 3) + k2];
            float2 u20 = sv.in.U[r2*258 + (f << 3) + k2];
            float2 u21 = sv.in.U[r2*258 + ((16+f) << 3) + k2];
            float wA = sv.in.W[(d2*2+0)*128 + (f << 3) + k2];
            float wB = sv.in.W[(d2*2+1)*128 + (f << 3) + k2];
            tracc.x += wA*(uu.x*u20.x + uu.y*u20.y) + wB*(uu.x*u21.x + uu.y*u21.y);
            tracc.y += wA*(uu.y*u20.x - uu.x*u20.y) + wB*(uu.y*u21.x - uu.x*u21.y);
        }

        // T[m=e*8+k] = hh0[k]*W[0][e][f][k] + hh1[k]*W[1][e][f][k]; write m-pair tiles
        {
            float4 w00a = W4[0*32 + 2*f], w00b = W4[0*32 + 2*f + 1];
            float4 w01a = W4[1*32 + 2*f], w01b = W4[1*32 + 2*f + 1];
            float4 w10a = W4[2*32 + 2*f], w10b = W4[2*32 + 2*f + 1];
            float4 w11a = W4[3*32 + 2*f], w11b = W4[3*32 + 2*f + 1];
            #define TW(E, KP, W0Q, W1Q, C0, C1) { \
                float2 t0, t1; \
                t0.x = hh0[2*KP].x   * (W0Q).C0 + hh1[2*KP].x   * (W1Q).C0; \
                t0.y = hh0[2*KP].y   * (W0Q).C0 + hh1[2*KP].y   * (W1Q).C0; \
                t1.x = hh0[2*KP+1].x * (W0Q).C1 + hh1[2*KP+1].x * (W1Q).C1; \
                t1.y = hh0[2*KP+1].y * (W0Q).C1 + hh1[2*KP+1].y * (W1Q).C1; \
                tile[wbase + ((E)*4+(KP))*71 + tp] = make_float4(t0.x,t0.y,t1.x,t1.y); \
                huw[(E)*8+2*(KP)].x   += t0.x; huw[(E)*8+2*(KP)].y   += t0.y; \
                huw[(E)*8+2*(KP)+1].x += t1.x; huw[(E)*8+2*(KP)+1].y += t1.y; }
            TW(0, 0, w00a, w10a, x, y)
            TW(0, 1, w00a, w10a, z, w)
            TW(0, 2, w00b, w10b, x, y)
            TW(0, 3, w00b, w10b, z, w)
            TW(1, 0, w01a, w11a, x, y)
            TW(1, 1, w01a, w11a, z, w)
            TW(1, 2, w01b, w11b, x, y)
            TW(1, 3, w01b, w11b, z, w)
            #undef TW
            #pragma unroll
            for (int kp = 0; kp < 4; ++kp) {
                tile[wbase + (8+kp)*71 + tp]  =
                    make_float4(hh0[2*kp].x,hh0[2*kp].y,hh0[2*kp+1].x,hh0[2*kp+1].y);
                tile[wbase + (12+kp)*71 + tp] =
                    make_float4(hh1[2*kp].x,hh1[2*kp].y,hh1[2*kp+1].x,hh1[2*kp+1].y);
            }
        }

        // quad partial: qacc[i][j] += sum_m T[8*l8+i][m] * conj(H[8*llo+j][m])
        #pragma unroll 1
        for (int mp = 0; mp < 8; ++mp) {
            const float4* tb = &tile[wbase + mp*71 + 9*l8];
            const float4* hq = &tile[wbase + (8+mp)*71 + 9*llo];
            float4 tv[8], hv[8];
            #pragma unroll
            for (int i = 0; i < 8; ++i) tv[i] = tb[i];
            #pragma unroll
            for (int j = 0; j < 8; ++j) hv[j] = hq[j];
            #pragma unroll
            for (int i = 0; i < 8; ++i)
                #pragma unroll
                for (int j = 0; j < 8; ++j) {
                    qacc[i][j].x += tv[i].x*hv[j].x + tv[i].y*hv[j].y;
                    qacc[i][j].y += tv[i].y*hv[j].x - tv[i].x*hv[j].y;
                    qacc[i][j].x += tv[i].z*hv[j].z + tv[i].w*hv[j].w;
                    qacc[i][j].y += tv[i].w*hv[j].z - tv[i].z*hv[j].w;
                }
        }
    }

    // ---- tr_UWU: wave butterfly + LDS atomics ----
    #pragma unroll
    for (int off = 32; off; off >>= 1) {
        tracc.x += __shfl_xor(tracc.x, off);
        tracc.y += __shfl_xor(tracc.y, off);
    }
    if (ln == 0) { atomicAdd(&trUW[0], tracc.x); atomicAdd(&trUW[1], tracc.y); }

    // ---- huw dump into own (now dead) tile region ----
    {
        float4* dp = &tile[wbase + 9*ln];
        #pragma unroll
        for (int q = 0; q < 8; ++q)
            dp[q] = make_float4(huw[2*q].x, huw[2*q].y, huw[2*q+1].x, huw[2*q+1].y);
    }
    __syncthreads();                                   // B0

    // ---- RHS = sum_w huw_w, thread owns cells (t=tid>>3, m=2*(tid&7)+{0,1}) ----
    const int rt = tid >> 3, rmp = tid & 7;
    float4 rhs = make_float4(0.f, 0.f, 0.f, 0.f);
    #pragma unroll
    for (int w = 0; w < 8; ++w) {
        float4 v = tile[w*TPF4 + 9*rt + rmp];
        rhs.x += v.x; rhs.y += v.y; rhs.z += v.z; rhs.w += v.w;
    }
    __syncthreads();                                   // B1

    // ---- qacc merge tree (staging slots S0-2 above Aug in tile region) ----
    #define ST_WRITE(SLOT) { \
        float4* sp = &tile[SBASE + (SLOT)*SSTR + ln*33]; \
        _Pragma("unroll") \
        for (int i = 0; i < 8; ++i) \
            _Pragma("unroll") \
            for (int j2 = 0; j2 < 4; ++j2) \
                sp[i*4+j2] = make_float4(qacc[i][2*j2].x, qacc[i][2*j2].y, \
                                         qacc[i][2*j2+1].x, qacc[i][2*j2+1].y); }
    #define ST_ADD(SLOT) { \
        const float4* sp = &tile[SBASE + (SLOT)*SSTR + ln*33]; \
        _Pragma("unroll") \
        for (int i = 0; i < 8; ++i) \
            _Pragma("unroll") \
            for (int j2 = 0; j2 < 4; ++j2) { \
                float4 v = sp[i*4+j2]; \
                qacc[i][2*j2].x   += v.x; qacc[i][2*j2].y   += v.y; \
                qacc[i][2*j2+1].x += v.z; qacc[i][2*j2+1].y += v.w; } }

    if (wv >= 4 && wv < 7) ST_WRITE(wv - 4)
    __syncthreads();                                   // B2
    if (wv < 3) ST_ADD(wv)
    __syncthreads();                                   // B3
    if (wv == 3) ST_WRITE(0)
    if (wv == 7) ST_WRITE(1)
    __syncthreads();                                   // B4
    if (wv == 0) ST_ADD(0)
    if (wv == 1) ST_ADD(1)
    __syncthreads();                                   // B5
    if (wv == 1) ST_WRITE(0)
    if (wv == 2) ST_WRITE(1)
    __syncthreads();                                   // B6

    const float trvx = 0.1f * trUW[0];
    const float trvy = 0.1f * trUW[1];
    if (wv == 0) {
        ST_ADD(0)
        ST_ADD(1)
        // write Aug main block (rows 8*l8+i, col pairs 8*llo+2*j2)
        #pragma unroll
        for (int i = 0; i < 8; ++i) {
            int row = 8*l8 + i;
            #pragma unroll
            for (int j2 = 0; j2 < 4; ++j2) {
                float2 c0 = qacc[i][2*j2], c1 = qacc[i][2*j2+1];
                if (l8 == llo) {
                    if (i == 2*j2)     { c0.x += trvx; c0.y += trvy; }
                    if (i == 2*j2 + 1) { c1.x += trvx; c1.y += trvy; }
                }
                tile[row*AUGF4 + 4*llo + j2] = make_float4(c0.x, c0.y, c1.x, c1.y);
            }
        }
    }
    tile[rt*AUGF4 + 32 + rmp] = rhs;                   // Aug RHS cols 64..79
    __syncthreads();                                   // B7
    #undef ST_WRITE
    #undef ST_ADD

    // ---- Gauss-Jordan: register-resident rows, diagonal pivots (R6) ----
    const int gi = tid >> 3, gc = tid & 7;
    const int colbase = 10 * gc;
    const int lanebase = (tid & 63) & 56;
    float2* prow0 = &sv.gj.prow[0][0];
    float2* prow1 = &sv.gj.prow[1][0];

    float2 xr[10];
    {
        const float4* rp = &tile[gi*AUGF4 + 5*gc];
        float4 q0 = rp[0], q1 = rp[1], q2 = rp[2], q3 = rp[3], q4 = rp[4];
        xr[0] = make_float2(q0.x, q0.y); xr[1] = make_float2(q0.z, q0.w);
        xr[2] = make_float2(q1.x, q1.y); xr[3] = make_float2(q1.z, q1.w);
        xr[4] = make_float2(q2.x, q2.y); xr[5] = make_float2(q2.z, q2.w);
        xr[6] = make_float2(q3.x, q3.y); xr[7] = make_float2(q3.z, q3.w);
        xr[8] = make_float2(q4.x, q4.y); xr[9] = make_float2(q4.z, q4.w);
    }
    if (gi == 0) {
        float4* wp = (float4*)&prow0[colbase];
        wp[0] = make_float4(xr[0].x, xr[0].y, xr[1].x, xr[1].y);
        wp[1] = make_float4(xr[2].x, xr[2].y, xr[3].x, xr[3].y);
        wp[2] = make_float4(xr[4].x, xr[4].y, xr[5].x, xr[5].y);
        wp[3] = make_float4(xr[6].x, xr[6].y, xr[7].x, xr[7].y);
        wp[4] = make_float4(xr[8].x, xr[8].y, xr[9].x, xr[9].y);
    }
    __syncthreads();                                   // B8

    float2 myipv = make_float2(0.f, 0.f);

    #pragma unroll 1
    for (int ks = 0; ks < 64; ++ks) {
        float2* pb = (ks & 1) ? prow1 : prow0;
        float2* pn = (ks & 1) ? prow0 : prow1;
        const float4* pp = (const float4*)&pb[colbase];
        float4 p0 = pp[0], p1 = pp[1], p2 = pp[2], p3 = pp[3], p4 = pp[4];
        float2 pr[10];
        pr[0] = make_float2(p0.x, p0.y); pr[1] = make_float2(p0.z, p0.w);
        pr[2] = make_float2(p1.x, p1.y); pr[3] = make_float2(p1.z, p1.w);
        pr[4] = make_float2(p2.x, p2.y); pr[5] = make_float2(p2.z, p2.w);
        pr[6] = make_float2(p3.x, p3.y); pr[7] = make_float2(p3.z, p3.w);
        pr[8] = make_float2(p4.x, p4.y); pr[9] = make_float2(p4.z, p4.w);

        float2 z = pb[ks];
        float  zi = 1.0f / (z.x*z.x + z.y*z.y);
        float2 ipv = make_float2(z.x*zi, -z.y*zi);

        float2 cand = make_float2(0.f, 0.f);
        #pragma unroll
        for (int c = 0; c < 10; ++c)
            if (colbase + c == ks) cand = xr[c];
        int srcl = lanebase + (ks / 10);
        float2 Lv;
        Lv.x = __shfl(cand.x, srcl);
        Lv.y = __shfl(cand.y, srcl);

        if (gi == ks) {
            myipv = ipv;
        } else {
            float2 L = cmul(Lv, ipv);
            #pragma unroll
            for (int c = 0; c < 10; ++c) {
                xr[c].x -= L.x*pr[c].x - L.y*pr[c].y;
                xr[c].y -= L.x*pr[c].y + L.y*pr[c].x;
            }
        }
        if (gi == ks + 1) {
            float4* wp = (float4*)&pn[colbase];
            wp[0] = make_float4(xr[0].x, xr[0].y, xr[1].x, xr[1].y);
            wp[1] = make_float4(xr[2].x, xr[2].y, xr[3].x, xr[3].y);
            wp[2] = make_float4(xr[4].x, xr[4].y, xr[5].x, xr[5].y);
            wp[3] = make_float4(xr[6].x, xr[6].y, xr[7].x, xr[7].y);
            wp[4] = make_float4(xr[8].x, xr[8].y, xr[9].x, xr[9].y);
        }
        __syncthreads();
    }

    // ---- extract solution (cols 64..79), normalize, write ----
    float ss = 0.f;
    if (gc == 6) {
        #pragma unroll
        for (int c = 4; c < 10; ++c) {
            float2 xv = cmul(xr[c], myipv);
            ss += xv.x*xv.x + xv.y*xv.y;
            sv.gj.xout[gi][c - 4] = xv;
        }
    } else if (gc == 7) {
        #pragma unroll
        for (int c = 0; c < 10; ++c) {
            float2 xv = cmul(xr[c], myipv);
            ss += xv.x*xv.x + xv.y*xv.y;
            sv.gj.xout[gi][6 + c] = xv;
        }
    }
    #pragma unroll
    for (int off = 32; off; off >>= 1) ss += __shfl_xor(ss, off);
    if (ln == 0) fred[wv] = ss;
    __syncthreads();
    float total = 0.f;
    #pragma unroll
    for (int w = 0; w < 8; ++w) total += fred[w];
    float invn = rsqrtf(total);
    #pragma unroll
    for (int q = 0; q < 2; ++q) {
        int m = tid + q*512;
        float2 v = sv.gj.xout[m >> 4][m & 15];
        out[(size_t)b * 1024 + m] = make_float2(v.x*invn, v.y*invn);
    }
}

extern "C" void kernel_launch(void* const* d_in, const int* in_sizes, int n_in,
                              void* d_out, int out_size, void* d_ws, size_t ws_size,
                              hipStream_t stream) {
    const float* channel    = (const float*)d_in[0];
    const float* prediction = (const float*)d_in[1];
    int batch = in_sizes[0] / 65536;   // 256
    uw2v_kernel<<<dim3(batch), dim3(512), 0, stream>>>(channel, prediction,
                                                       (float2*)d_out);
}

// Round 8
// 169.310 us; speedup vs baseline: 1.2617x; 1.2617x over previous
//
#include <hip/hip_runtime.h>
#include <math.h>

// NT=64, NR=4, DK=2, KU=8, BR=16, BATCH=256
// channel:    [B][64][4][16][16] f32 (last dim: 8 re, 8 im)
// prediction: [B][2560] = U[4][2][16][16] ++ W[2][2][16][8]
// out:        [B][64][2][8][2] f32
//
// R8 = R6 (proven 120us) + two quad-phase changes:
//  (a) m-paired float4 T/H tiles -> b128 LDS ops, half the instructions
//  (b) split accumulators (accA/accB) -> fmaf pairs fusable to v_pk_fma_f32
// Everything else (halves-over-f, butterfly HHU, merge, GJ reg-rows, epilogue)
// is R6 verbatim. R7's 8x8 tiles + merge tree spilled to scratch (84MB WRITE).

#define SAUG 84   // float2 stride of Aug rows
#define STP  65   // float4 stride of paired TtP/HtP rows

namespace {
union alignas(16) ShU {
    struct { float4 TtP[2][2][8][STP]; float4 HtP[2][2][8][STP]; } p1; // 66560 B
    float2 Aug[64][SAUG];                                              // 43008 B
};
union alignas(16) ShV {
    struct { float2 U[4 * 258]; float W[512]; } in;                    // 10304 B
    float2 xout[64][17];                                               // 8704 B
};
}

__device__ __forceinline__ float2 cmul(float2 x, float2 y) {
    return make_float2(x.x * y.x - x.y * y.y, x.x * y.y + x.y * y.x);
}

__global__ __launch_bounds__(512, 1)
void uw2v_kernel(const float* __restrict__ channel,
                 const float* __restrict__ prediction,
                 float2* __restrict__ out)
{
    __shared__ ShU sh;
    __shared__ ShV sv;
    __shared__ alignas(16) float2 prow[2][80];   // pivot-row double buffer
    __shared__ float2 redbuf[8];
    __shared__ float  fred[8];

    const int b   = blockIdx.x;
    const int tid = threadIdx.x;
    const int wv  = tid >> 6;
    const float* pred = prediction + (size_t)b * 2560;
    const float* chan = channel + (size_t)b * 65536;

    // ---- load U (re/im merged, padded per-r stride) and W ----
    #pragma unroll
    for (int i = 0; i < 2; ++i) {
        int m = tid + i * 512;                       // [r][d][f][k]
        int r = m >> 8, d = (m >> 7) & 1, f = (m >> 3) & 15, k = m & 7;
        const float* src = pred + (((r * 2 + d) * 16 + f) << 4);
        sv.in.U[r * 258 + ((d * 16 + f) << 3) + k] = make_float2(src[k], src[k + 8]);
    }
    sv.in.W[tid] = pred[2048 + tid];
    __syncthreads();

    const int half = tid >> 8;
    const int lt   = tid & 255;
    const int t4 = lt >> 2, r4 = lt & 3;
    const int a  = lt >> 4, bb = lt & 15;
    const int bit0 = r4 & 1, bit1 = (r4 >> 1) & 1;
    const int kkb  = 4 * bit0 + 2 * bit1;            // owned k-slice base (even)
    const int mpb  = kkb >> 1;                       // owned m-pair row (0..3)
    const int fbase = half << 3;
    const int tr_r = lt >> 5, tr_d = (lt >> 4) & 1, tr_e = (lt >> 3) & 1, tr_k = lt & 7;

    // split accumulators: accA = sum t_re*h, accB = sum t_im*h (h = (re,im))
    float2 accA[4][4], accB[4][4];
    #pragma unroll
    for (int i = 0; i < 4; ++i)
        #pragma unroll
        for (int j = 0; j < 4; ++j) {
            accA[i][j] = make_float2(0.f, 0.f);
            accB[i][j] = make_float2(0.f, 0.f);
        }
    float2 huw[4] = {make_float2(0,0), make_float2(0,0), make_float2(0,0), make_float2(0,0)};
    float2 tracc  = make_float2(0.f, 0.f);

    const float* hbase = chan + ((t4 * 4 + r4) << 8) + (fbase << 4);

    #pragma unroll 1
    for (int fi = 0; fi < 8; ++fi) {
        const int f = fbase + fi;
        const float4 ca = *(const float4*)(hbase + (fi << 4) + 0);
        const float4 cb = *(const float4*)(hbase + (fi << 4) + 4);
        const float4 ci = *(const float4*)(hbase + (fi << 4) + 8);
        const float4 cd = *(const float4*)(hbase + (fi << 4) + 12);

        const float4* U0p = (const float4*)&sv.in.U[r4 * 258 + (f << 3)];        // d=0
        const float4* U1p = (const float4*)&sv.in.U[r4 * 258 + ((16 + f) << 3)]; // d=1
        const float4 u0q0 = U0p[0], u0q1 = U0p[1], u0q2 = U0p[2], u0q3 = U0p[3];
        const float4 u1q0 = U1p[0], u1q1 = U1p[1], u1q2 = U1p[2], u1q3 = U1p[3];

        // partials: val0[k] = conj(H)*U (d=0, m=k), val1[k] (d=1, m=8+k)
        float2 val0[8], val1[8];
        #define MK2(K, HR, HI, U0R, U0I, U1R, U1I) \
            val0[K] = make_float2((HR)*(U0R) + (HI)*(U0I), (HR)*(U0I) - (HI)*(U0R)); \
            val1[K] = make_float2((HR)*(U1R) + (HI)*(U1I), (HR)*(U1I) - (HI)*(U1R));
        MK2(0, ca.x, ci.x, u0q0.x, u0q0.y, u1q0.x, u1q0.y)
        MK2(1, ca.y, ci.y, u0q0.z, u0q0.w, u1q0.z, u1q0.w)
        MK2(2, ca.z, ci.z, u0q1.x, u0q1.y, u1q1.x, u1q1.y)
        MK2(3, ca.w, ci.w, u0q1.z, u0q1.w, u1q1.z, u1q1.w)
        MK2(4, cb.x, cd.x, u0q2.x, u0q2.y, u1q2.x, u1q2.y)
        MK2(5, cb.y, cd.y, u0q2.z, u0q2.w, u1q2.z, u1q2.w)
        MK2(6, cb.z, cd.z, u0q3.x, u0q3.y, u1q3.x, u1q3.y)
        MK2(7, cb.w, cd.w, u0q3.z, u0q3.w, u1q3.z, u1q3.w)
        #undef MK2

        // stage 1 (xor 1): keep k in {4*bit0 .. 4*bit0+3}
        float2 s1d0[4], s1d1[4];
        #pragma unroll
        for (int q = 0; q < 4; ++q) {
            float2 k0 = bit0 ? val0[4 + q] : val0[q];
            float2 n0 = bit0 ? val0[q]     : val0[4 + q];
            float2 k1 = bit0 ? val1[4 + q] : val1[q];
            float2 n1 = bit0 ? val1[q]     : val1[4 + q];
            n0.x = __shfl_xor(n0.x, 1); n0.y = __shfl_xor(n0.y, 1);
            n1.x = __shfl_xor(n1.x, 1); n1.y = __shfl_xor(n1.y, 1);
            s1d0[q] = make_float2(k0.x + n0.x, k0.y + n0.y);
            s1d1[q] = make_float2(k1.x + n1.x, k1.y + n1.y);
        }
        // stage 2 (xor 2): keep q in {2*bit1, 2*bit1+1} -> hh[kkb+jj]
        float2 h0[2], h1[2];
        #pragma unroll
        for (int jj = 0; jj < 2; ++jj) {
            float2 k0 = bit1 ? s1d0[2 + jj] : s1d0[jj];
            float2 n0 = bit1 ? s1d0[jj]     : s1d0[2 + jj];
            float2 k1 = bit1 ? s1d1[2 + jj] : s1d1[jj];
            float2 n1 = bit1 ? s1d1[jj]     : s1d1[2 + jj];
            n0.x = __shfl_xor(n0.x, 2); n0.y = __shfl_xor(n0.y, 2);
            n1.x = __shfl_xor(n1.x, 2); n1.y = __shfl_xor(n1.y, 2);
            h0[jj] = make_float2(k0.x + n0.x, k0.y + n0.y);
            h1[jj] = make_float2(k1.x + n1.x, k1.y + n1.y);
        }

        // tr_UWU partial (128 lanes per half; wave-uniform branch)
        if (lt < 128) {
            float w   = sv.in.W[((tr_d * 2 + tr_e) * 16 + f) * 8 + tr_k];
            float2 u1 = sv.in.U[tr_r * 258 + ((tr_d * 16 + f) << 3) + tr_k];
            float2 u2 = sv.in.U[tr_r * 258 + ((tr_e * 16 + f) << 3) + tr_k];
            tracc.x += w * (u1.x * u2.x + u1.y * u2.y);
            tracc.y += w * (u1.y * u2.x - u1.x * u2.y);
        }

        // T pairs + H pairs (b128 writes, m-pair rows)
        const int p = fi & 1;
        #pragma unroll
        for (int e = 0; e < 2; ++e) {
            float w0a = sv.in.W[(e * 16 + f) * 8 + kkb];
            float w0b = sv.in.W[(e * 16 + f) * 8 + kkb + 1];
            float w1a = sv.in.W[((2 + e) * 16 + f) * 8 + kkb];
            float w1b = sv.in.W[((2 + e) * 16 + f) * 8 + kkb + 1];
            float2 tva = make_float2(h0[0].x * w0a + h1[0].x * w1a,
                                     h0[0].y * w0a + h1[0].y * w1a);
            float2 tvb = make_float2(h0[1].x * w0b + h1[1].x * w1b,
                                     h0[1].y * w0b + h1[1].y * w1b);
            sh.p1.TtP[p][half][e * 4 + mpb][t4] = make_float4(tva.x, tva.y, tvb.x, tvb.y);
            huw[e * 2 + 0].x += tva.x; huw[e * 2 + 0].y += tva.y;
            huw[e * 2 + 1].x += tvb.x; huw[e * 2 + 1].y += tvb.y;
        }
        sh.p1.HtP[p][half][mpb][t4]     = make_float4(h0[0].x, h0[0].y, h0[1].x, h0[1].y);
        sh.p1.HtP[p][half][4 + mpb][t4] = make_float4(h1[0].x, h1[0].y, h1[1].x, h1[1].y);
        __syncthreads();

        // quad: accA/accB [i][j] over m-pairs (b128 reads, broadcast-friendly)
        #pragma unroll
        for (int mp = 0; mp < 8; ++mp) {
            float4 tq[4], hq[4];
            #pragma unroll
            for (int i = 0; i < 4; ++i) tq[i] = sh.p1.TtP[p][half][mp][a + 16 * i];
            #pragma unroll
            for (int j = 0; j < 4; ++j) hq[j] = sh.p1.HtP[p][half][mp][bb + 16 * j];
            #pragma unroll
            for (int i = 0; i < 4; ++i)
                #pragma unroll
                for (int j = 0; j < 4; ++j) {
                    float2 va = accA[i][j], vb = accB[i][j];
                    va.x = fmaf(tq[i].x, hq[j].x, va.x);
                    va.y = fmaf(tq[i].x, hq[j].y, va.y);
                    vb.x = fmaf(tq[i].y, hq[j].x, vb.x);
                    vb.y = fmaf(tq[i].y, hq[j].y, vb.y);
                    va.x = fmaf(tq[i].z, hq[j].z, va.x);
                    va.y = fmaf(tq[i].z, hq[j].w, va.y);
                    vb.x = fmaf(tq[i].w, hq[j].z, vb.x);
                    vb.y = fmaf(tq[i].w, hq[j].w, vb.y);
                    accA[i][j] = va; accB[i][j] = vb;
                }
        }
    }

    // ---- tr_UWU block reduction ----
    #pragma unroll
    for (int off = 32; off; off >>= 1) {
        tracc.x += __shfl_xor(tracc.x, off);
        tracc.y += __shfl_xor(tracc.y, off);
    }
    if ((tid & 63) == 0) redbuf[wv] = tracc;
    __syncthreads();
    float2 trv = make_float2(0.f, 0.f);
    #pragma unroll
    for (int w = 0; w < 8; ++w) { trv.x += redbuf[w].x; trv.y += redbuf[w].y; }
    trv.x *= 0.1f; trv.y *= 0.1f;

    // ---- merge halves into Aug = [quad + trv*I | HUW] ----
    // qacc = (accA.x + accB.y, accB.x - accA.y)
    if (half == 0) {
        #pragma unroll
        for (int i = 0; i < 4; ++i)
            #pragma unroll
            for (int j = 0; j < 4; ++j) {
                float2 v = make_float2(accA[i][j].x + accB[i][j].y,
                                       accB[i][j].x - accA[i][j].y);
                int row = a + 16 * i, col = bb + 16 * j;
                if (row == col) { v.x += trv.x; v.y += trv.y; }
                sh.Aug[row][col] = v;
            }
        #pragma unroll
        for (int e = 0; e < 2; ++e)
            #pragma unroll
            for (int jj = 0; jj < 2; ++jj)
                sh.Aug[t4][64 + e * 8 + kkb + jj] = huw[e * 2 + jj];
    }
    __syncthreads();
    if (half == 1) {
        #pragma unroll
        for (int i = 0; i < 4; ++i)
            #pragma unroll
            for (int j = 0; j < 4; ++j) {
                int row = a + 16 * i, col = bb + 16 * j;
                float2 v = sh.Aug[row][col];
                v.x += accA[i][j].x + accB[i][j].y;
                v.y += accB[i][j].x - accA[i][j].y;
                sh.Aug[row][col] = v;
            }
        #pragma unroll
        for (int e = 0; e < 2; ++e)
            #pragma unroll
            for (int jj = 0; jj < 2; ++jj) {
                int col = 64 + e * 8 + kkb + jj;
                float2 v = sh.Aug[t4][col];
                v.x += huw[e * 2 + jj].x; v.y += huw[e * 2 + jj].y;
                sh.Aug[t4][col] = v;
            }
    }
    __syncthreads();

    // ---- Gauss-Jordan: register-resident rows, diagonal pivots (R6) ----
    const int gi = tid >> 3, gc = tid & 7;
    const int colbase = 10 * gc;
    const int lanebase = (tid & 63) & 56;

    float2 xr[10];
    {
        const float4* rp = (const float4*)&sh.Aug[gi][colbase];
        float4 q0 = rp[0], q1 = rp[1], q2 = rp[2], q3 = rp[3], q4 = rp[4];
        xr[0] = make_float2(q0.x, q0.y); xr[1] = make_float2(q0.z, q0.w);
        xr[2] = make_float2(q1.x, q1.y); xr[3] = make_float2(q1.z, q1.w);
        xr[4] = make_float2(q2.x, q2.y); xr[5] = make_float2(q2.z, q2.w);
        xr[6] = make_float2(q3.x, q3.y); xr[7] = make_float2(q3.z, q3.w);
        xr[8] = make_float2(q4.x, q4.y); xr[9] = make_float2(q4.z, q4.w);
    }
    if (gi == 0) {
        float4* wp = (float4*)&prow[0][colbase];
        wp[0] = make_float4(xr[0].x, xr[0].y, xr[1].x, xr[1].y);
        wp[1] = make_float4(xr[2].x, xr[2].y, xr[3].x, xr[3].y);
        wp[2] = make_float4(xr[4].x, xr[4].y, xr[5].x, xr[5].y);
        wp[3] = make_float4(xr[6].x, xr[6].y, xr[7].x, xr[7].y);
        wp[4] = make_float4(xr[8].x, xr[8].y, xr[9].x, xr[9].y);
    }
    __syncthreads();

    float2 myipv = make_float2(0.f, 0.f);

    #pragma unroll 1
    for (int ks = 0; ks < 64; ++ks) {
        const int pb = ks & 1;
        const float4* pp = (const float4*)&prow[pb][colbase];
        float4 p0 = pp[0], p1 = pp[1], p2 = pp[2], p3 = pp[3], p4 = pp[4];
        float2 pr[10];
        pr[0] = make_float2(p0.x, p0.y); pr[1] = make_float2(p0.z, p0.w);
        pr[2] = make_float2(p1.x, p1.y); pr[3] = make_float2(p1.z, p1.w);
        pr[4] = make_float2(p2.x, p2.y); pr[5] = make_float2(p2.z, p2.w);
        pr[6] = make_float2(p3.x, p3.y); pr[7] = make_float2(p3.z, p3.w);
        pr[8] = make_float2(p4.x, p4.y); pr[9] = make_float2(p4.z, p4.w);

        float2 z = prow[pb][ks];
        float  zi = 1.0f / (z.x * z.x + z.y * z.y);
        float2 ipv = make_float2(z.x * zi, -z.y * zi);

        float2 cand = make_float2(0.f, 0.f);
        #pragma unroll
        for (int c = 0; c < 10; ++c)
            if (colbase + c == ks) cand = xr[c];
        int srcl = lanebase + (ks / 10);
        float2 Lv;
        Lv.x = __shfl(cand.x, srcl);
        Lv.y = __shfl(cand.y, srcl);

        if (gi == ks) {
            myipv = ipv;
        } else {
            float2 L = cmul(Lv, ipv);
            #pragma unroll
            for (int c = 0; c < 10; ++c) {
                xr[c].x -= L.x * pr[c].x - L.y * pr[c].y;
                xr[c].y -= L.x * pr[c].y + L.y * pr[c].x;
            }
        }
        if (gi == ks + 1) {
            float4* wp = (float4*)&prow[pb ^ 1][colbase];
            wp[0] = make_float4(xr[0].x, xr[0].y, xr[1].x, xr[1].y);
            wp[1] = make_float4(xr[2].x, xr[2].y, xr[3].x, xr[3].y);
            wp[2] = make_float4(xr[4].x, xr[4].y, xr[5].x, xr[5].y);
            wp[3] = make_float4(xr[6].x, xr[6].y, xr[7].x, xr[7].y);
            wp[4] = make_float4(xr[8].x, xr[8].y, xr[9].x, xr[9].y);
        }
        __syncthreads();
    }

    // ---- extract solution (cols 64..79), normalize, write ----
    float ss = 0.f;
    if (gc == 6) {
        #pragma unroll
        for (int c = 4; c < 10; ++c) {
            float2 xv = cmul(xr[c], myipv);
            ss += xv.x * xv.x + xv.y * xv.y;
            sv.xout[gi][c - 4] = xv;
        }
    } else if (gc == 7) {
        #pragma unroll
        for (int c = 0; c < 10; ++c) {
            float2 xv = cmul(xr[c], myipv);
            ss += xv.x * xv.x + xv.y * xv.y;
            sv.xout[gi][6 + c] = xv;
        }
    }
    #pragma unroll
    for (int off = 32; off; off >>= 1) ss += __shfl_xor(ss, off);
    if ((tid & 63) == 0) fred[wv] = ss;
    __syncthreads();
    float total = 0.f;
    #pragma unroll
    for (int w = 0; w < 8; ++w) total += fred[w];
    float invn = rsqrtf(total);
    #pragma unroll
    for (int q = 0; q < 2; ++q) {
        int m = tid + q * 512;
        float2 v = sv.xout[m >> 4][m & 15];
        out[(size_t)b * 1024 + m] = make_float2(v.x * invn, v.y * invn);
    }
}

extern "C" void kernel_launch(void* const* d_in, const int* in_sizes, int n_in,
                              void* d_out, int out_size, void* d_ws, size_t ws_size,
                              hipStream_t stream) {
    const float* channel    = (const float*)d_in[0];
    const float* prediction = (const float*)d_in[1];
    int batch = in_sizes[0] / 65536;   // 256
    uw2v_kernel<<<dim3(batch), dim3(512), 0, stream>>>(channel, prediction,
                                                       (float2*)d_out);
}